// Round 1
// baseline (321.380 us; speedup 1.0000x reference)
//
#include <hip/hip_runtime.h>
#include <math.h>

// Problem constants (from reference)
#define NG   1024        // graphs
#define NP   256         // nodes per graph
#define EPG  4096        // edges per graph
#define ETOT 4194304     // total edges
#define NTOT (NG * NP)   // 262144 nodes
#define FIN  7
#define HD   64
#define KC   50
#define CHK  64          // rows per K2 chunk
#define NCH  4           // chunks per graph
#define FST  72          // f16 LDS row stride in k2 (144 B rows, 16B-aligned)
#define ASTR 264         // k3 f16 row stride: 132 words = 4 mod 32 (2-way free)
#define ASTW 132         // ASTR in u32 words
#define TSC  0.00390625f // tail scale 1/256 (exact): keeps h2*s, t*s in f16 range
#define TSCI 256.0f      // inverse

// NOTE (R2): __launch_bounds__ 2nd arg acts as CUDA-style min BLOCKS/CU.
// NOTE (R3): LDS atomic scatter -> counting-sort gather.
// NOTE (R4): persistent per-lane arrays spill at the VGPR cap -> wave-row regs.
// NOTE (R5): GEMV-style phases are latency-bound -> f16 MFMA GEMMs.
// NOTE (R8): f16 scalar gathers add a cvt per element -> regressed.
// NOTE (R10/R11): dense-A slabs + MFMA; stride 264 kills 16-way conflicts.
// NOTE (R12): one 1024-thread block/graph for k3; stage once, reg-accumulate.
// NOTE (R13): weights preconverted once; xp/G moved into k3; partials deleted.
// NOTE (R14): k4 fused into k3 tail (VALU: 12.6 us/block).
// NOTE (R15): MFMA tail NaN'd: Ap@xp reaches O(1e5) > f16 max; h2f stored inf,
// inf-inf=NaN in log_softmax. R16: scale h2/t by 1/256 through the relu
// (positively homogeneous, exact pow2), unscale in the fp32 logit fold.
// NOTE (R0 this session): GPU broker timed out; resubmitting the verified
// 321.4us kernel unchanged to obtain baseline counters before editing.

typedef __attribute__((ext_vector_type(8))) _Float16 v8h;
typedef __attribute__((ext_vector_type(4))) float v4f;

// Inter-kernel intermediates as statics: no hipMalloc, graph-capture safe.
// Every element is rewritten each launch before being read.
__device__ float g_xagg[NTOT * 8];                          // x+agg, padded to 8
__device__ __align__(16) _Float16 g_W1bT[HD * HD];          // W1b^T [d][j] f16
__device__ __align__(16) _Float16 g_WpT[HD * HD];           // Wp^T  [k][d] f16
__device__ __align__(16) _Float16 g_W2aT[HD * HD];          // W2a^T [d2][d] f16
__device__ __align__(16) _Float16 g_W2bT[HD * HD];          // W2b^T [j][d2] f16
__device__ __align__(16) _Float16 g_ShT[(size_t)NG * KC * 256]; // S^T [k][n] f16
__device__ __align__(16) _Float16 g_hT[(size_t)NG * HD * 256];  // h^T [d][n] f16

__global__ void zero_ws(float* ws) {
    if (threadIdx.x < 4) ws[threadIdx.x] = 0.f;
}

// one-shot weight f16 preconversion (same work every launch; capture-safe)
__global__ void kw_conv(const float* __restrict__ W1b, const float* __restrict__ Wp,
                        const float* __restrict__ W2a, const float* __restrict__ W2b) {
    const int tid = threadIdx.x;
    for (int i = tid; i < HD * HD; i += 1024) {
        int d = i >> 6, j = i & 63;
        g_W1bT[i] = (_Float16)W1b[j * HD + d];      // [d][j]
        g_W2aT[i] = (_Float16)W2a[j * HD + d];      // [d2][d]
        g_W2bT[i] = (_Float16)W2b[j * HD + d];      // [j][d2]
    }
    for (int i = tid; i < HD * HD; i += 1024) {
        int k = i >> 6, d = i & 63;
        g_WpT[i] = (k < KC) ? (_Float16)Wp[d * KC + k] : (_Float16)0.f;
    }
}

// ws[0]=sumA2, ws[1]=sum S logS, ws[2]=trace(Ap)=sum(A.SSt), ws[3]=||G||^2
__global__ void finalize_k(const float* __restrict__ ws, float* __restrict__ out) {
    if (threadIdx.x == 0) {
        float num = ws[0] - 2.f * ws[2] + ws[3];
        float link = sqrtf(fmaxf(num, 0.f)) / 67108864.0f;   // / (B*n*n)
        float ent  = -ws[1] / 262144.0f;                     // / N
        out[2048] = link + ent;
    }
}

__device__ __forceinline__ float blockReduceN(float v, float* red, int nw) {
    __syncthreads();
    #pragma unroll
    for (int o = 32; o > 0; o >>= 1) v += __shfl_down(v, o);
    if ((threadIdx.x & 63) == 0) red[threadIdx.x >> 6] = v;
    __syncthreads();
    float r = 0.f;
    if (threadIdx.x == 0) {
        for (int i = 0; i < nw; ++i) r += red[i];
    }
    return r;
}

// ---- K1a: di counting sort + gather GIN aggregation -------------------------
// LDS ~25 KB -> 3 blocks/CU
__launch_bounds__(512, 3)
__global__ void k1a_sort(const int* __restrict__ esrc, const int* __restrict__ edst,
                         const float* __restrict__ x)
{
    __shared__ unsigned short cells[EPG];       // 8 KB
    __shared__ unsigned char ssi[EPG];          // 4 KB  (di-sorted si)
    __shared__ float xt8[NP * 8];               // 8 KB  (x, stride 8, pad 0)
    __shared__ unsigned int hist_di[256], cur_di[256];
    __shared__ unsigned int roff_di[NP + 1];

    const int g = blockIdx.x, tid = threadIdx.x;
    const int lane = tid & 63, wid = tid >> 6;

    if (tid < 256) hist_di[tid] = 0u;
    __syncthreads();

    for (int e = tid; e < EPG; e += 512) {
        int s = esrc[g * EPG + e] & (NP - 1);
        int d = edst[g * EPG + e] & (NP - 1);
        cells[e] = (unsigned short)((s << 8) | d);
        atomicAdd(&hist_di[d], 1u);
    }
    for (int i = tid; i < NP * 8; i += 512) {
        int n = i >> 3, f = i & 7;
        xt8[i] = (f < FIN) ? x[g * NP * FIN + n * FIN + f] : 0.f;
    }
    __syncthreads();

    // exclusive scan (wave 0)
    if (wid == 0) {
        unsigned carry = 0;
        for (int c = 0; c < 4; ++c) {
            unsigned v = hist_di[c * 64 + lane];
            unsigned s = v;
            #pragma unroll
            for (int o = 1; o < 64; o <<= 1) {
                unsigned t = __shfl_up(s, o);
                if (lane >= o) s += t;
            }
            unsigned excl = s - v + carry;
            roff_di[c * 64 + lane] = excl;
            cur_di[c * 64 + lane] = excl;
            carry += __shfl(s, 63);
        }
        if (lane == 0) roff_di[NP] = EPG;
    }
    __syncthreads();

    for (int e = tid; e < EPG; e += 512) {
        int c = cells[e]; int si = c >> 8, di = c & 255;
        unsigned p2 = atomicAdd(&cur_di[di], 1u);
        ssi[p2] = (unsigned char)si;
    }
    __syncthreads();

    // gather agg: 8 lanes per node (f = lane&7), write x+agg
    {
        const int gidx = tid >> 3, f = tid & 7;
        for (int n = gidx; n < NP; n += 64) {
            int beg = roff_di[n], end = roff_di[n + 1];
            float a = xt8[n * 8 + f];
            for (int e = beg; e < end; ++e)
                a += xt8[ssi[e] * 8 + f];
            g_xagg[g * NP * 8 + n * 8 + f] = a;
        }
    }
}

// ---- K2: MFMA f16 — MLP1, h-GEMM, P-GEMM, softmax; emits S^T, h^T -----------
__launch_bounds__(512, 2)
__global__ void k2_mlp(const float* __restrict__ W1a, const float* __restrict__ b1a,
                       const float* __restrict__ b1b, const float* __restrict__ bp,
                       float* __restrict__ ws)
{
    __shared__ __align__(16) float xt[CHK * 8];          // 2 KB
    __shared__ __align__(16) _Float16 t1b[CHK * FST];    // 9.2 KB  t1   [n][j]
    __shared__ __align__(16) _Float16 W1bT[HD * FST];    // 9.2 KB  W1b^T[d][j]
    __shared__ __align__(16) _Float16 WpT[HD * FST];     // 9.2 KB  Wp^T [k][d]
    __shared__ __align__(16) _Float16 hN[CHK * FST];     // 9.2 KB  h    [n][d]
    __shared__ __align__(16) _Float16 hT[HD * FST];      // 9.2 KB  h^T  [d][n]
    __shared__ __align__(16) _Float16 StT[HD * FST];     // 9.2 KB  S^T  [k][n]
    __shared__ __align__(16) float Pf[CHK * 66];         // 16.9 KB P    [n][k]
    __shared__ float red[8];

    const int b = blockIdx.x, rbase = b * CHK, tid = threadIdx.x;
    const int g = b >> 2, ch = b & 3;
    const int lane = tid & 63, wid = tid >> 6;
    const int l15 = lane & 15, quad = lane >> 4;
    const int fko = quad * 8;

    xt[tid] = g_xagg[rbase * 8 + tid];
    // stage preconverted weights (u32 vector copies, no cvt)
    for (int i = tid; i < HD * 32; i += 512) {
        int r = i >> 5, o = i & 31;
        ((unsigned int*)W1bT)[r * 36 + o] = ((const unsigned int*)g_W1bT)[r * 32 + o];
        ((unsigned int*)WpT)[r * 36 + o]  = ((const unsigned int*)g_WpT)[r * 32 + o];
    }
    __syncthreads();

    // t1 = relu((x+agg) @ W1a + b1a)
    {
        float w1r[FIN];
        #pragma unroll
        for (int f = 0; f < FIN; ++f) w1r[f] = W1a[f * HD + lane];
        float br = b1a[lane];
        for (int n = wid; n < CHK; n += 8) {
            float a = br;
            #pragma unroll
            for (int f = 0; f < FIN; ++f) a += xt[n * 8 + f] * w1r[f];
            t1b[n * FST + lane] = (_Float16)fmaxf(a, 0.f);
        }
    }
    __syncthreads();

    // h = t1 @ W1b + b1b
    for (int t = wid * 2; t < wid * 2 + 2; ++t) {
        int mt = (t >> 2) << 4, nt = (t & 3) << 4;
        v4f acc = {0.f, 0.f, 0.f, 0.f};
        #pragma unroll
        for (int ks = 0; ks < 2; ++ks) {
            v8h af = *(const v8h*)&t1b[(mt + l15) * FST + ks * 32 + fko];
            v8h bf = *(const v8h*)&W1bT[(nt + l15) * FST + ks * 32 + fko];
            acc = __builtin_amdgcn_mfma_f32_16x16x32_f16(af, bf, acc, 0, 0, 0);
        }
        int d = nt + l15;
        float bv = b1b[d];
        #pragma unroll
        for (int r = 0; r < 4; ++r) {
            int m = mt + quad * 4 + r;
            _Float16 hv = (_Float16)(acc[r] + bv);
            hN[m * FST + d] = hv;
            hT[d * FST + m] = hv;
        }
    }
    __syncthreads();

    // persist h^T chunk (coalesced u32)
    for (int i = tid; i < HD * 32; i += 512) {
        int d = i >> 5, o = i & 31;
        unsigned w = *(const unsigned int*)&hT[d * FST + 2 * o];
        ((unsigned int*)g_hT)[((size_t)g * HD + d) * 128 + ch * 32 + o] = w;
    }

    // P = h @ Wp + bp
    for (int t = wid * 2; t < wid * 2 + 2; ++t) {
        int mt = (t >> 2) << 4, nt = (t & 3) << 4;
        v4f acc = {0.f, 0.f, 0.f, 0.f};
        #pragma unroll
        for (int ks = 0; ks < 2; ++ks) {
            v8h af = *(const v8h*)&hN[(mt + l15) * FST + ks * 32 + fko];
            v8h bf = *(const v8h*)&WpT[(nt + l15) * FST + ks * 32 + fko];
            acc = __builtin_amdgcn_mfma_f32_16x16x32_f16(af, bf, acc, 0, 0, 0);
        }
        int kcol = nt + l15;
        if (kcol < KC) {
            float bv = bp[kcol];
            #pragma unroll
            for (int r = 0; r < 4; ++r)
                Pf[(mt + quad * 4 + r) * 66 + kcol] = acc[r] + bv;
        }
    }
    __syncthreads();

    // softmax -> StT f16 [k][n], entropy partial
    float entL = 0.f;
    for (int n = wid; n < CHK; n += 8) {
        float a = (lane < KC) ? Pf[n * 66 + lane] : -INFINITY;
        float m = a;
        #pragma unroll
        for (int o = 32; o > 0; o >>= 1) m = fmaxf(m, __shfl_xor(m, o));
        float e = expf(a - m);
        float ss = e;
        #pragma unroll
        for (int o = 32; o > 0; o >>= 1) ss += __shfl_xor(ss, o);
        float s = e / ss;
        if (lane < KC) {
            StT[lane * FST + n] = (_Float16)s;
            entL += s * logf(s + 1e-15f);
        }
    }
    __syncthreads();

    // persist S^T chunk (coalesced u32)
    for (int i = tid; i < KC * 32; i += 512) {
        int k = i >> 5, o = i & 31;
        unsigned w = *(const unsigned int*)&StT[k * FST + 2 * o];
        ((unsigned int*)g_ShT)[((size_t)g * KC + k) * 128 + ch * 32 + o] = w;
    }

    float r = blockReduceN(entL, red, 8);
    if (tid == 0) atomicAdd(&ws[1], r);
}

// ---- K3_fused: dense-A slabs + MFMA AS/Ap/xp/G + MFMA dense-GIN head --------
// One 1024-thread block per graph. Slab phase: u.a (cnt/T1T); tail phase: u.b
// (Apf/xpT/h2f/tf, f16 stride 72). Tail intermediates scaled by 1/256 to stay
// in f16 range (relu is positively homogeneous; unscaled in fp32 logit fold).
__launch_bounds__(1024, 1)
__global__ void k3_fused(const int* __restrict__ esrc, const int* __restrict__ edst,
                         const float* __restrict__ b2a, const float* __restrict__ b2b,
                         const float* __restrict__ Wl,  const float* __restrict__ bl,
                         float* __restrict__ out, float* __restrict__ ws)
{
    __shared__ __align__(16) union {
        struct {
            unsigned int cnt[64 * ASTW];         // 33 KB; becomes f16 A[64][264]
            _Float16 T1T[64 * 72];               // 9 KB   AS^T [c][nrow]
        } a;
        struct {
            _Float16 Apf[64 * 72];               // 9.2 KB  Ap  [k][l] (pads 0)
            _Float16 xpT[64 * 72];               // 9.2 KB  xp^T[d][l]
            _Float16 h2f[64 * 72];               // 9.2 KB  h2*s [k][d]
            _Float16 tf[64 * 72];                // 9.2 KB  t*s  [k][d2]
        } b;
    } u;
    __shared__ __align__(16) _Float16 ST[64 * ASTR]; // 33 KB  S^T [k][n] padded
    __shared__ __align__(16) _Float16 HT[64 * ASTR]; // 33 KB  h^T [d][n] padded
    __shared__ unsigned short cells[EPG];            // 8 KB
    __shared__ float red[16];

    const int g = blockIdx.x, tid = threadIdx.x;
    const int lane = tid & 63, wid = tid >> 6;       // wid 0..15
    const int l15 = lane & 15, quad = lane >> 4, fko = quad * 8;
    const int mt = (wid >> 2) << 4, nt = (wid & 3) << 4;   // this wave's tile

    // stage S^T and h^T once (zero S^T rows k>=50; zero col pads on both)
    for (int i = tid; i < 64 * 128; i += 1024) {
        int k = i >> 7, o = i & 127;
        ((unsigned int*)ST)[k * ASTW + o] = (k < KC)
            ? ((const unsigned int*)g_ShT)[((size_t)g * KC + k) * 128 + o] : 0u;
        ((unsigned int*)HT)[k * ASTW + o] =
            ((const unsigned int*)g_hT)[((size_t)g * HD + k) * 128 + o];
    }
    for (int i = tid; i < 64 * 4; i += 1024) {
        ((unsigned int*)ST)[(i >> 2) * ASTW + 128 + (i & 3)] = 0u;
        ((unsigned int*)HT)[(i >> 2) * ASTW + 128 + (i & 3)] = 0u;
    }
    // stage edges once
    for (int e = tid; e < EPG; e += 1024) {
        int s = esrc[g * EPG + e] & (NP - 1);
        int d = edst[g * EPG + e] & (NP - 1);
        cells[e] = (unsigned short)((s << 8) | d);
    }
    __syncthreads();

    float sumA2 = 0.f;
    v4f ap  = {0.f, 0.f, 0.f, 0.f};                  // Ap tile
    v4f axp = {0.f, 0.f, 0.f, 0.f};                  // xp tile
    v4f ag  = {0.f, 0.f, 0.f, 0.f};                  // G tile

    for (int ch = 0; ch < 4; ++ch) {
        for (int i = tid; i < 64 * ASTW; i += 1024) u.a.cnt[i] = 0u;
        __syncthreads();

        // count this slab's cells (rows s in [ch*64, ch*64+64))
        int rlo = ch << 6;
        for (int e = tid; e < EPG; e += 1024) {
            int c = cells[e];
            int sr = (c >> 8) - rlo;
            if ((unsigned)sr < 64u) {
                int d = c & 255;
                atomicAdd(&u.a.cnt[sr * ASTW + (d >> 1)], (d & 1) ? 0x10000u : 1u);
            }
        }
        __syncthreads();

        // sum(A^2) partial + in-place convert counts -> f16 (pads stay 0)
        for (int i = tid; i < 64 * ASTW; i += 1024) {
            unsigned v = u.a.cnt[i];
            float m0 = (float)(v & 0xffffu), m1 = (float)(v >> 16);
            sumA2 += m0 * m0 + m1 * m1;
            union { unsigned uu; _Float16 h[2]; } cv;
            cv.h[0] = (_Float16)m0; cv.h[1] = (_Float16)m1;
            u.a.cnt[i] = cv.uu;
        }
        __syncthreads();

        const _Float16* Af = (const _Float16*)u.a.cnt;   // A slab [64][264]

        // AS_slab = A_slab @ S : 16 tiles, 1 per wave
        {
            v4f acc = {0.f, 0.f, 0.f, 0.f};
            #pragma unroll
            for (int ks = 0; ks < 8; ++ks) {
                v8h af = *(const v8h*)&Af[(mt + l15) * ASTR + ks * 32 + fko];
                v8h bf = *(const v8h*)&ST[(nt + l15) * ASTR + ks * 32 + fko];
                acc = __builtin_amdgcn_mfma_f32_16x16x32_f16(af, bf, acc, 0, 0, 0);
            }
            int c = nt + l15;
            #pragma unroll
            for (int r = 0; r < 4; ++r)
                u.a.T1T[c * 72 + mt + quad * 4 + r] = (_Float16)acc[r];
        }
        __syncthreads();

        // Ap += S_slab^T @ AS_slab; xp += S_slab^T @ h_slab; G += S^T S (slab)
        #pragma unroll
        for (int ks = 0; ks < 2; ++ks) {
            int ko = (ch << 6) + ks * 32 + fko;
            v8h af = *(const v8h*)&ST[(mt + l15) * ASTR + ko];
            v8h bt = *(const v8h*)&u.a.T1T[(nt + l15) * 72 + ks * 32 + fko];
            v8h bh = *(const v8h*)&HT[(nt + l15) * ASTR + ko];
            v8h bs = *(const v8h*)&ST[(nt + l15) * ASTR + ko];
            ap  = __builtin_amdgcn_mfma_f32_16x16x32_f16(af, bt, ap, 0, 0, 0);
            axp = __builtin_amdgcn_mfma_f32_16x16x32_f16(af, bh, axp, 0, 0, 0);
            ag  = __builtin_amdgcn_mfma_f32_16x16x32_f16(af, bs, ag, 0, 0, 0);
        }
        __syncthreads();    // u.a reused next slab
    }

    // scalars from tiles; write f16 Ap / xp^T (tiles are zero beyond KC by
    // construction: S rows >=50 are zero -> ap/axp rows&cols >=50 are zero)
    float tr = 0.f, g2 = 0.f;
    {
        int c = nt + l15;
        #pragma unroll
        for (int r = 0; r < 4; ++r) {
            int k = mt + quad * 4 + r;
            u.b.Apf[k * 72 + c] = (_Float16)ap[r];
            u.b.xpT[c * 72 + k] = (_Float16)axp[r];
            if (k < KC && c < KC) {
                if (k == c) tr += ap[r];
                g2 += ag[r] * ag[r];
            }
        }
    }

    float rA = blockReduceN(sumA2, red, 16);   // internal barriers fence u.b
    float rT = blockReduceN(tr, red, 16);
    float rG = blockReduceN(g2, red, 16);
    if (tid == 0) {
        atomicAdd(&ws[0], rA);
        atomicAdd(&ws[2], rT);
        atomicAdd(&ws[3], rG);
    }
    __syncthreads();

    // ---- MFMA tail: h2 = xp + Ap @ xp (fp32 acc init = live axp tile);
    //      store h2*TSC in f16 (overflow-proof) ----
    {
        v4f hacc = axp;
        #pragma unroll
        for (int ks = 0; ks < 2; ++ks) {
            v8h af = *(const v8h*)&u.b.Apf[(mt + l15) * 72 + ks * 32 + fko];
            v8h bf = *(const v8h*)&u.b.xpT[(nt + l15) * 72 + ks * 32 + fko];
            hacc = __builtin_amdgcn_mfma_f32_16x16x32_f16(af, bf, hacc, 0, 0, 0);
        }
        int d = nt + l15;
        #pragma unroll
        for (int r = 0; r < 4; ++r)
            u.b.h2f[(mt + quad * 4 + r) * 72 + d] = (_Float16)(hacc[r] * TSC);
    }
    __syncthreads();

    // t*s = relu(h2s @ W2a + s*b2a)   (B-frags from global preconverted f16)
    {
        float bv = b2a[nt + l15] * TSC;
        v4f tacc = {bv, bv, bv, bv};
        #pragma unroll
        for (int ks = 0; ks < 2; ++ks) {
            v8h af = *(const v8h*)&u.b.h2f[(mt + l15) * 72 + ks * 32 + fko];
            v8h bf = *(const v8h*)&g_W2aT[(nt + l15) * 64 + ks * 32 + fko];
            tacc = __builtin_amdgcn_mfma_f32_16x16x32_f16(af, bf, tacc, 0, 0, 0);
        }
        int d2 = nt + l15;
        #pragma unroll
        for (int r = 0; r < 4; ++r)
            u.b.tf[(mt + quad * 4 + r) * 72 + d2] = (_Float16)fmaxf(tacc[r], 0.f);
    }
    __syncthreads();

    // h3 = (t*s)@W2b * 256 + b2b; fold mean over k (<KC) and Wl in fp32
    float l0 = 0.f, l1 = 0.f;
    {
        v4f oacc = {0.f, 0.f, 0.f, 0.f};
        #pragma unroll
        for (int ks = 0; ks < 2; ++ks) {
            v8h af = *(const v8h*)&u.b.tf[(mt + l15) * 72 + ks * 32 + fko];
            v8h bf = *(const v8h*)&g_W2bT[(nt + l15) * 64 + ks * 32 + fko];
            oacc = __builtin_amdgcn_mfma_f32_16x16x32_f16(af, bf, oacc, 0, 0, 0);
        }
        int j = nt + l15;
        float bv = b2b[j];
        float wl0 = Wl[j * 2], wl1 = Wl[j * 2 + 1];
        #pragma unroll
        for (int r = 0; r < 4; ++r) {
            int k = mt + quad * 4 + r;
            if (k < KC) {
                float h3v = oacc[r] * TSCI + bv;
                l0 += h3v * wl0; l1 += h3v * wl1;
            }
        }
    }

    float rl0 = blockReduceN(l0, red, 16);
    float rl1 = blockReduceN(l1, red, 16);
    if (tid == 0) {
        float g0 = bl[0] + rl0 * (1.f / KC);
        float g1 = bl[1] + rl1 * (1.f / KC);
        float mm = fmaxf(g0, g1);
        float lse = mm + logf(expf(g0 - mm) + expf(g1 - mm));
        out[2 * g]     = g0 - lse;
        out[2 * g + 1] = g1 - lse;
    }
}

extern "C" void kernel_launch(void* const* d_in, const int* in_sizes, int n_in,
                              void* d_out, int out_size, void* d_ws, size_t ws_size,
                              hipStream_t stream) {
    const float* x    = (const float*)d_in[0];
    const float* W1a  = (const float*)d_in[1];
    const float* b1a  = (const float*)d_in[2];
    const float* W1b  = (const float*)d_in[3];
    const float* b1b  = (const float*)d_in[4];
    const float* Wp   = (const float*)d_in[5];
    const float* bp   = (const float*)d_in[6];
    const float* W2a  = (const float*)d_in[7];
    const float* b2a  = (const float*)d_in[8];
    const float* W2b  = (const float*)d_in[9];
    const float* b2b  = (const float*)d_in[10];
    const float* Wl   = (const float*)d_in[11];
    const float* bl   = (const float*)d_in[12];
    const int*   eidx = (const int*)d_in[13];   // [2, E] int32
    float* out = (float*)d_out;
    float* ws  = (float*)d_ws;

    zero_ws<<<1, 64, 0, stream>>>(ws);
    kw_conv<<<1, 1024, 0, stream>>>(W1b, Wp, W2a, W2b);
    k1a_sort<<<NG, 512, 0, stream>>>(eidx, eidx + ETOT, x);
    k2_mlp<<<NG * NCH, 512, 0, stream>>>(W1a, b1a, b1b, bp, ws);
    k3_fused<<<NG, 1024, 0, stream>>>(eidx, eidx + ETOT,
                                      b2a, b2b, Wl, bl, out, ws);
    finalize_k<<<1, 64, 0, stream>>>(ws, out);
}

// Round 2
// 315.876 us; speedup vs baseline: 1.0174x; 1.0174x over previous
//
#include <hip/hip_runtime.h>
#include <math.h>

// Problem constants (from reference)
#define NG   1024        // graphs
#define NP   256         // nodes per graph
#define EPG  4096        // edges per graph
#define ETOT 4194304     // total edges
#define NTOT (NG * NP)   // 262144 nodes
#define FIN  7
#define HD   64
#define KC   50
#define CHK  64          // rows per phase-2 chunk
#define FST  72          // f16 LDS row stride in phase 2 (144 B rows)
#define ASTR 264         // f16 row stride for ST/HT/A: 132 words = 4 mod 32
#define ASTW 132         // ASTR in u32 words
#define TSC  0.00390625f // tail scale 1/256 (exact)
#define TSCI 256.0f      // inverse

// NOTE (R2..R16): see prior session ladder (sort-gather, MFMA GEMMs, dense-A
// slabs, 1024-thr k3, fused tail, 1/256 tail scaling for f16 range).
// NOTE (R1 this session): counters showed k3 latency-bound (Mfma 5.9%, VALU
// 25%, HBM 5.5%, occ 41%) and k1a+k2 ~200us producing 136MB of g_xagg/g_hT/
// g_ShT round-trips. Fused all three into one per-graph megakernel: phase 2
// writes S^T/h^T straight into the LDS buffers phase 3 reads; cells decoded
// once; weight B-frags read from L2-hot preconverted globals. LDS ~127KB,
// 1 block/CU, 4 rounds.

typedef __attribute__((ext_vector_type(8))) _Float16 v8h;
typedef __attribute__((ext_vector_type(4))) float v4f;

// f16 preconverted weights (rewritten every launch; capture-safe)
__device__ __align__(16) _Float16 g_W1bT[HD * HD];          // W1b^T [d][j]
__device__ __align__(16) _Float16 g_WpT[HD * HD];           // Wp^T  [k][d]
__device__ __align__(16) _Float16 g_W2aT[HD * HD];          // W2a^T [d2][d]
__device__ __align__(16) _Float16 g_W2bT[HD * HD];          // W2b^T [j][d2]

__global__ void zero_ws(float* ws) {
    if (threadIdx.x < 4) ws[threadIdx.x] = 0.f;
}

__global__ void kw_conv(const float* __restrict__ W1b, const float* __restrict__ Wp,
                        const float* __restrict__ W2a, const float* __restrict__ W2b) {
    const int tid = threadIdx.x;
    for (int i = tid; i < HD * HD; i += 1024) {
        int d = i >> 6, j = i & 63;
        g_W1bT[i] = (_Float16)W1b[j * HD + d];      // [d][j]
        g_W2aT[i] = (_Float16)W2a[j * HD + d];      // [d2][d]
        g_W2bT[i] = (_Float16)W2b[j * HD + d];      // [j][d2]
    }
    for (int i = tid; i < HD * HD; i += 1024) {
        int k = i >> 6, d = i & 63;
        g_WpT[i] = (k < KC) ? (_Float16)Wp[d * KC + k] : (_Float16)0.f;
    }
}

// ws[0]=sumA2, ws[1]=sum S logS, ws[2]=trace(Ap), ws[3]=||G||^2
__global__ void finalize_k(const float* __restrict__ ws, float* __restrict__ out) {
    if (threadIdx.x == 0) {
        float num = ws[0] - 2.f * ws[2] + ws[3];
        float link = sqrtf(fmaxf(num, 0.f)) / 67108864.0f;   // / (B*n*n)
        float ent  = -ws[1] / 262144.0f;                     // / N
        out[2048] = link + ent;
    }
}

__device__ __forceinline__ float blockReduceN(float v, float* red, int nw) {
    __syncthreads();
    #pragma unroll
    for (int o = 32; o > 0; o >>= 1) v += __shfl_down(v, o);
    if ((threadIdx.x & 63) == 0) red[threadIdx.x >> 6] = v;
    __syncthreads();
    float r = 0.f;
    if (threadIdx.x == 0) {
        for (int i = 0; i < nw; ++i) r += red[i];
    }
    return r;
}

// ---- MEGA: per-graph fused pipeline -----------------------------------------
// Phase 1: edge decode + di counting sort + gather GIN agg  -> xagg (LDS)
// Phase 2: MLP1 + h-GEMM + P-GEMM + softmax (4 chunks)      -> HT, ST (LDS)
// Phase 3: dense-A slabs + AS/Ap/xp/G MFMA + dense-GIN head -> out
__launch_bounds__(1024, 1)
__global__ void mega(const int* __restrict__ esrc, const int* __restrict__ edst,
                     const float* __restrict__ x,
                     const float* __restrict__ W1a, const float* __restrict__ b1a,
                     const float* __restrict__ b1b, const float* __restrict__ bp,
                     const float* __restrict__ b2a, const float* __restrict__ b2b,
                     const float* __restrict__ Wl,  const float* __restrict__ bl,
                     float* __restrict__ out, float* __restrict__ ws)
{
    __shared__ __align__(16) _Float16 ST[64 * ASTR];  // 33.8 KB  S^T [k][n]
    __shared__ __align__(16) _Float16 HT[64 * ASTR];  // 33.8 KB  h^T [d][n]
    __shared__ unsigned short cells[EPG];             // 8 KB  (s<<8|d)
    __shared__ __align__(16) float xagg[NP * 8];      // 8 KB  x+agg, pad 8
    __shared__ __align__(16) union {
        struct {                                      // phase 1 (15.4 KB)
            unsigned char ssi[EPG];
            float xt8[NP * 8];
            unsigned int hist[256], cur[256], roff[NP + 1];
        } k1;
        struct {                                      // phase 2 (35.3 KB)
            _Float16 t1b[CHK * FST];
            _Float16 hN[CHK * FST];
            float Pf[CHK * 66];
        } k2;
        struct {                                      // phase 3 slab (43 KB)
            unsigned int cnt[64 * ASTW];
            _Float16 T1T[64 * 72];
        } a;
        struct {                                      // phase 3 tail (36.9 KB)
            _Float16 Apf[64 * 72];
            _Float16 xpT[64 * 72];
            _Float16 h2f[64 * 72];
            _Float16 tf[64 * 72];
        } b;
    } u;
    __shared__ float red[16];

    const int g = blockIdx.x, tid = threadIdx.x;
    const int lane = tid & 63, wid = tid >> 6;        // wid 0..15
    const int l15 = lane & 15, quad = lane >> 4, fko = quad * 8;
    const int mt = (wid >> 2) << 4, nt = (wid & 3) << 4;

    // ---- init: zero ST/HT (rows k>=50 and col pads must be 0 for phase 3) --
    for (int i = tid; i < 64 * ASTW; i += 1024) {
        ((unsigned int*)ST)[i] = 0u;
        ((unsigned int*)HT)[i] = 0u;
    }
    if (tid < 256) u.k1.hist[tid] = 0u;
    __syncthreads();

    // ---- phase 1: decode edges + histogram + stage x ----
    for (int e = tid; e < EPG; e += 1024) {
        int s = esrc[g * EPG + e] & (NP - 1);
        int d = edst[g * EPG + e] & (NP - 1);
        cells[e] = (unsigned short)((s << 8) | d);
        atomicAdd(&u.k1.hist[d], 1u);
    }
    for (int i = tid; i < NP * 8; i += 1024) {
        int n = i >> 3, f = i & 7;
        u.k1.xt8[i] = (f < FIN) ? x[g * NP * FIN + n * FIN + f] : 0.f;
    }
    __syncthreads();

    // exclusive scan (wave 0)
    if (wid == 0) {
        unsigned carry = 0;
        for (int c = 0; c < 4; ++c) {
            unsigned v = u.k1.hist[c * 64 + lane];
            unsigned s = v;
            #pragma unroll
            for (int o = 1; o < 64; o <<= 1) {
                unsigned t = __shfl_up(s, o);
                if (lane >= o) s += t;
            }
            unsigned excl = s - v + carry;
            u.k1.roff[c * 64 + lane] = excl;
            u.k1.cur[c * 64 + lane] = excl;
            carry += __shfl(s, 63);
        }
        if (lane == 0) u.k1.roff[NP] = EPG;
    }
    __syncthreads();

    for (int e = tid; e < EPG; e += 1024) {
        int c = cells[e]; int si = c >> 8, di = c & 255;
        unsigned p2 = atomicAdd(&u.k1.cur[di], 1u);
        u.k1.ssi[p2] = (unsigned char)si;
    }
    __syncthreads();

    // gather agg: 8 lanes per node -> xagg (LDS)
    {
        const int gi = tid >> 3, f = tid & 7;   // 128 node groups
        for (int n = gi; n < NP; n += 128) {
            int beg = u.k1.roff[n], end = u.k1.roff[n + 1];
            float a = u.k1.xt8[n * 8 + f];
            for (int e = beg; e < end; ++e)
                a += u.k1.xt8[u.k1.ssi[e] * 8 + f];
            xagg[n * 8 + f] = a;
        }
    }
    __syncthreads();

    // ---- phase 2: MLP1 + h + P + softmax, 4 chunks of 64 rows ----
    float entL = 0.f;
    {
        float w1r[FIN];
        #pragma unroll
        for (int f = 0; f < FIN; ++f) w1r[f] = W1a[f * HD + lane];
        float b1r = b1a[lane];

        for (int ch2 = 0; ch2 < 4; ++ch2) {
            const int rb = ch2 * 64;
            // t1 = relu((x+agg) @ W1a + b1a)
            for (int n = wid; n < CHK; n += 16) {
                float a = b1r;
                #pragma unroll
                for (int f = 0; f < FIN; ++f) a += xagg[(rb + n) * 8 + f] * w1r[f];
                u.k2.t1b[n * FST + lane] = (_Float16)fmaxf(a, 0.f);
            }
            __syncthreads();

            // h = t1 @ W1b + b1b  (1 tile/wave; B-frag from L2-hot global)
            {
                v4f acc = {0.f, 0.f, 0.f, 0.f};
                #pragma unroll
                for (int ks = 0; ks < 2; ++ks) {
                    v8h af = *(const v8h*)&u.k2.t1b[(mt + l15) * FST + ks * 32 + fko];
                    v8h bf = *(const v8h*)&g_W1bT[(nt + l15) * HD + ks * 32 + fko];
                    acc = __builtin_amdgcn_mfma_f32_16x16x32_f16(af, bf, acc, 0, 0, 0);
                }
                int d = nt + l15;
                float bv = b1b[d];
                #pragma unroll
                for (int r = 0; r < 4; ++r) {
                    int m = mt + quad * 4 + r;
                    _Float16 hv = (_Float16)(acc[r] + bv);
                    u.k2.hN[m * FST + d] = hv;
                    HT[d * ASTR + rb + m] = hv;     // direct into phase-3 buffer
                }
            }
            __syncthreads();

            // P = h @ Wp + bp
            {
                v4f acc = {0.f, 0.f, 0.f, 0.f};
                #pragma unroll
                for (int ks = 0; ks < 2; ++ks) {
                    v8h af = *(const v8h*)&u.k2.hN[(mt + l15) * FST + ks * 32 + fko];
                    v8h bf = *(const v8h*)&g_WpT[(nt + l15) * HD + ks * 32 + fko];
                    acc = __builtin_amdgcn_mfma_f32_16x16x32_f16(af, bf, acc, 0, 0, 0);
                }
                int kcol = nt + l15;
                if (kcol < KC) {
                    float bv = bp[kcol];
                    #pragma unroll
                    for (int r = 0; r < 4; ++r)
                        u.k2.Pf[(mt + quad * 4 + r) * 66 + kcol] = acc[r] + bv;
                }
            }
            __syncthreads();

            // softmax rows -> ST (direct), entropy partial
            for (int n = wid; n < CHK; n += 16) {
                float a = (lane < KC) ? u.k2.Pf[n * 66 + lane] : -INFINITY;
                float m = a;
                #pragma unroll
                for (int o = 32; o > 0; o >>= 1) m = fmaxf(m, __shfl_xor(m, o));
                float e = expf(a - m);
                float ss = e;
                #pragma unroll
                for (int o = 32; o > 0; o >>= 1) ss += __shfl_xor(ss, o);
                float s = e / ss;
                if (lane < KC) {
                    ST[lane * ASTR + rb + n] = (_Float16)s;
                    entL += s * logf(s + 1e-15f);
                }
            }
            __syncthreads();
        }
    }
    {
        float rE = blockReduceN(entL, red, 16);
        if (tid == 0) atomicAdd(&ws[1], rE);
    }
    // blockReduceN's trailing barrier fences ST/HT complete + u free

    // ---- phase 3: dense-A slabs + MFMA AS/Ap/xp/G ----
    float sumA2 = 0.f;
    v4f ap  = {0.f, 0.f, 0.f, 0.f};
    v4f axp = {0.f, 0.f, 0.f, 0.f};
    v4f ag  = {0.f, 0.f, 0.f, 0.f};

    for (int ch = 0; ch < 4; ++ch) {
        for (int i = tid; i < 64 * ASTW; i += 1024) u.a.cnt[i] = 0u;
        __syncthreads();

        int rlo = ch << 6;
        for (int e = tid; e < EPG; e += 1024) {
            int c = cells[e];
            int sr = (c >> 8) - rlo;
            if ((unsigned)sr < 64u) {
                int d = c & 255;
                atomicAdd(&u.a.cnt[sr * ASTW + (d >> 1)], (d & 1) ? 0x10000u : 1u);
            }
        }
        __syncthreads();

        for (int i = tid; i < 64 * ASTW; i += 1024) {
            unsigned v = u.a.cnt[i];
            float m0 = (float)(v & 0xffffu), m1 = (float)(v >> 16);
            sumA2 += m0 * m0 + m1 * m1;
            union { unsigned uu; _Float16 h[2]; } cv;
            cv.h[0] = (_Float16)m0; cv.h[1] = (_Float16)m1;
            u.a.cnt[i] = cv.uu;
        }
        __syncthreads();

        const _Float16* Af = (const _Float16*)u.a.cnt;

        // AS_slab = A_slab @ S
        {
            v4f acc = {0.f, 0.f, 0.f, 0.f};
            #pragma unroll
            for (int ks = 0; ks < 8; ++ks) {
                v8h af = *(const v8h*)&Af[(mt + l15) * ASTR + ks * 32 + fko];
                v8h bf = *(const v8h*)&ST[(nt + l15) * ASTR + ks * 32 + fko];
                acc = __builtin_amdgcn_mfma_f32_16x16x32_f16(af, bf, acc, 0, 0, 0);
            }
            int c = nt + l15;
            #pragma unroll
            for (int r = 0; r < 4; ++r)
                u.a.T1T[c * 72 + mt + quad * 4 + r] = (_Float16)acc[r];
        }
        __syncthreads();

        // Ap += S^T @ AS; xp += S^T @ h; G += S^T S (slab K-range)
        #pragma unroll
        for (int ks = 0; ks < 2; ++ks) {
            int ko = (ch << 6) + ks * 32 + fko;
            v8h af = *(const v8h*)&ST[(mt + l15) * ASTR + ko];
            v8h bt = *(const v8h*)&u.a.T1T[(nt + l15) * 72 + ks * 32 + fko];
            v8h bh = *(const v8h*)&HT[(nt + l15) * ASTR + ko];
            v8h bs = *(const v8h*)&ST[(nt + l15) * ASTR + ko];
            ap  = __builtin_amdgcn_mfma_f32_16x16x32_f16(af, bt, ap, 0, 0, 0);
            axp = __builtin_amdgcn_mfma_f32_16x16x32_f16(af, bh, axp, 0, 0, 0);
            ag  = __builtin_amdgcn_mfma_f32_16x16x32_f16(af, bs, ag, 0, 0, 0);
        }
        __syncthreads();
    }

    // scalars + f16 Ap / xp^T into tail buffers
    float tr = 0.f, g2 = 0.f;
    {
        int c = nt + l15;
        #pragma unroll
        for (int r = 0; r < 4; ++r) {
            int k = mt + quad * 4 + r;
            u.b.Apf[k * 72 + c] = (_Float16)ap[r];
            u.b.xpT[c * 72 + k] = (_Float16)axp[r];
            if (k < KC && c < KC) {
                if (k == c) tr += ap[r];
                g2 += ag[r] * ag[r];
            }
        }
    }

    float rA = blockReduceN(sumA2, red, 16);
    float rT = blockReduceN(tr, red, 16);
    float rG = blockReduceN(g2, red, 16);
    if (tid == 0) {
        atomicAdd(&ws[0], rA);
        atomicAdd(&ws[2], rT);
        atomicAdd(&ws[3], rG);
    }
    __syncthreads();

    // ---- MFMA tail: h2 = xp + Ap @ xp, scaled by 1/256 ----
    {
        v4f hacc = axp;
        #pragma unroll
        for (int ks = 0; ks < 2; ++ks) {
            v8h af = *(const v8h*)&u.b.Apf[(mt + l15) * 72 + ks * 32 + fko];
            v8h bf = *(const v8h*)&u.b.xpT[(nt + l15) * 72 + ks * 32 + fko];
            hacc = __builtin_amdgcn_mfma_f32_16x16x32_f16(af, bf, hacc, 0, 0, 0);
        }
        int d = nt + l15;
        #pragma unroll
        for (int r = 0; r < 4; ++r)
            u.b.h2f[(mt + quad * 4 + r) * 72 + d] = (_Float16)(hacc[r] * TSC);
    }
    __syncthreads();

    // t*s = relu(h2s @ W2a + s*b2a)
    {
        float bv = b2a[nt + l15] * TSC;
        v4f tacc = {bv, bv, bv, bv};
        #pragma unroll
        for (int ks = 0; ks < 2; ++ks) {
            v8h af = *(const v8h*)&u.b.h2f[(mt + l15) * 72 + ks * 32 + fko];
            v8h bf = *(const v8h*)&g_W2aT[(nt + l15) * 64 + ks * 32 + fko];
            tacc = __builtin_amdgcn_mfma_f32_16x16x32_f16(af, bf, tacc, 0, 0, 0);
        }
        int d2 = nt + l15;
        #pragma unroll
        for (int r = 0; r < 4; ++r)
            u.b.tf[(mt + quad * 4 + r) * 72 + d2] = (_Float16)fmaxf(tacc[r], 0.f);
    }
    __syncthreads();

    // h3 = (t*s)@W2b * 256 + b2b; fold mean over k and Wl in fp32
    float l0 = 0.f, l1 = 0.f;
    {
        v4f oacc = {0.f, 0.f, 0.f, 0.f};
        #pragma unroll
        for (int ks = 0; ks < 2; ++ks) {
            v8h af = *(const v8h*)&u.b.tf[(mt + l15) * 72 + ks * 32 + fko];
            v8h bf = *(const v8h*)&g_W2bT[(nt + l15) * 64 + ks * 32 + fko];
            oacc = __builtin_amdgcn_mfma_f32_16x16x32_f16(af, bf, oacc, 0, 0, 0);
        }
        int j = nt + l15;
        float bv = b2b[j];
        float wl0 = Wl[j * 2], wl1 = Wl[j * 2 + 1];
        #pragma unroll
        for (int r = 0; r < 4; ++r) {
            int k = mt + quad * 4 + r;
            if (k < KC) {
                float h3v = oacc[r] * TSCI + bv;
                l0 += h3v * wl0; l1 += h3v * wl1;
            }
        }
    }

    float rl0 = blockReduceN(l0, red, 16);
    float rl1 = blockReduceN(l1, red, 16);
    if (tid == 0) {
        float g0 = bl[0] + rl0 * (1.f / KC);
        float g1 = bl[1] + rl1 * (1.f / KC);
        float mm = fmaxf(g0, g1);
        float lse = mm + logf(expf(g0 - mm) + expf(g1 - mm));
        out[2 * g]     = g0 - lse;
        out[2 * g + 1] = g1 - lse;
    }
}

extern "C" void kernel_launch(void* const* d_in, const int* in_sizes, int n_in,
                              void* d_out, int out_size, void* d_ws, size_t ws_size,
                              hipStream_t stream) {
    const float* x    = (const float*)d_in[0];
    const float* W1a  = (const float*)d_in[1];
    const float* b1a  = (const float*)d_in[2];
    const float* W1b  = (const float*)d_in[3];
    const float* b1b  = (const float*)d_in[4];
    const float* Wp   = (const float*)d_in[5];
    const float* bp   = (const float*)d_in[6];
    const float* W2a  = (const float*)d_in[7];
    const float* b2a  = (const float*)d_in[8];
    const float* W2b  = (const float*)d_in[9];
    const float* b2b  = (const float*)d_in[10];
    const float* Wl   = (const float*)d_in[11];
    const float* bl   = (const float*)d_in[12];
    const int*   eidx = (const int*)d_in[13];   // [2, E] int32
    float* out = (float*)d_out;
    float* ws  = (float*)d_ws;

    zero_ws<<<1, 64, 0, stream>>>(ws);
    kw_conv<<<1, 1024, 0, stream>>>(W1b, Wp, W2a, W2b);
    mega<<<NG, 1024, 0, stream>>>(eidx, eidx + ETOT, x,
                                  W1a, b1a, b1b, bp,
                                  b2a, b2b, Wl, bl, out, ws);
    finalize_k<<<1, 64, 0, stream>>>(ws, out);
}